// Round 1
// baseline (238.458 us; speedup 1.0000x reference)
//
#include <hip/hip_runtime.h>

// Types for MFMA fragments (gfx950: v_mfma_f32_16x16x32_bf16 takes v8bf16)
typedef __attribute__((ext_vector_type(8))) __bf16 bf16x8;
typedef __attribute__((ext_vector_type(4))) float f32x4;

#define DI __device__ __forceinline__

// float -> bf16 bits, round-to-nearest-even (matches numpy/jax cast)
DI unsigned short f2bf(float x) {
  unsigned u = __float_as_uint(x);
  u += 0x7fffu + ((u >> 16) & 1u);
  return (unsigned short)(u >> 16);
}

// tanh via exp; absolute error ~5e-7, far below bf16 noise floor
DI float tanh_fast(float x) {
  float ax = fabsf(x);
  float e = __expf(-2.0f * ax);
  float t = (1.0f - e) / (1.0f + e);
  return x < 0.0f ? -t : t;
}

// ---------------------------------------------------------------------------
// Kernel 0: W [512(k),256(n)] fp32 -> Wt [256(n),512(k)] bf16 (k-contiguous,
// which is the B^T layout the MFMA B-fragment wants).
// ---------------------------------------------------------------------------
__global__ void k_wt(const float* __restrict__ W, unsigned short* __restrict__ Wt) {
  int n = blockIdx.x;      // 0..255
  int t = threadIdx.x;     // 0..127
  int k = t * 4;
  ushort4 v;
  v.x = f2bf(W[(k + 0) * 256 + n]);
  v.y = f2bf(W[(k + 1) * 256 + n]);
  v.z = f2bf(W[(k + 2) * 256 + n]);
  v.w = f2bf(W[(k + 3) * 256 + n]);
  *(ushort4*)&Wt[n * 512 + k] = v;
}

// ---------------------------------------------------------------------------
// Kernel 1: projection GEMM. M=65536 (lt rows then rt rows), K=512, N=256.
// Reads fp32 A once (full-N tile), converts to bf16 during LDS staging,
// MFMA accumulate fp32, epilogue tanh (+ diag scale for lt), bf16 store.
// BM=128, BN=256, BK=64, 512 threads (8 waves in 2x4 grid, 64x64 each).
// LDS row stride 72 shorts = 144 B: 16B-aligned for ds_read_b128, 36-bank
// shift per row -> only 2-way conflicts (free per m136).
// ---------------------------------------------------------------------------
#define G1_LDA 72

__global__ __launch_bounds__(512) void k_proj(
    const float* __restrict__ Alt, const float* __restrict__ Art,
    const unsigned short* __restrict__ Wt, const float* __restrict__ diag,
    unsigned short* __restrict__ Olt, unsigned short* __restrict__ Ort) {
  __shared__ __align__(16) unsigned short As[128 * G1_LDA];
  __shared__ __align__(16) unsigned short Bs[256 * G1_LDA];

  int bx = blockIdx.x;              // 0..511
  bool is_lt = bx < 256;
  int m0 = (is_lt ? bx : bx - 256) * 128;
  const float* A = (is_lt ? Alt : Art) + (size_t)m0 * 512;
  unsigned short* O = (is_lt ? Olt : Ort) + (size_t)m0 * 256;

  int tid  = threadIdx.x;
  int lane = tid & 63;
  int wid  = tid >> 6;              // 0..7
  int wm   = wid >> 2;              // 0..1 -> row half
  int wn   = wid & 3;               // 0..3 -> col quarter
  int l15  = lane & 15;
  int quad = lane >> 4;

  f32x4 zero = {0.0f, 0.0f, 0.0f, 0.0f};
  f32x4 acc[4][4];
#pragma unroll
  for (int i = 0; i < 4; i++)
#pragma unroll
    for (int j = 0; j < 4; j++) acc[i][j] = zero;

  for (int k0 = 0; k0 < 512; k0 += 64) {
    // Stage A: 128 rows x 64 k, fp32 -> bf16. 2048 float4 segments / 512 thr.
#pragma unroll
    for (int i = 0; i < 4; i++) {
      int seg = tid + i * 512;
      int r = seg >> 4;             // 0..127
      int c4 = seg & 15;            // float4 index within 64-k chunk
      f32x4 f = *(const f32x4*)&A[(size_t)r * 512 + k0 + c4 * 4];
      ushort4 v;
      v.x = f2bf(f.x); v.y = f2bf(f.y); v.z = f2bf(f.z); v.w = f2bf(f.w);
      *(ushort4*)&As[r * G1_LDA + c4 * 4] = v;
    }
    // Stage B: 256 n-rows x 64 k from Wt (already bf16, k-contiguous).
#pragma unroll
    for (int i = 0; i < 4; i++) {
      int seg = tid + i * 512;
      int n = seg >> 3;             // 0..255
      int kc = seg & 7;             // 8-bf16 segment
      *(uint4*)&Bs[n * G1_LDA + kc * 8] = *(const uint4*)&Wt[n * 512 + k0 + kc * 8];
    }
    __syncthreads();

#pragma unroll
    for (int ks = 0; ks < 2; ks++) {
      bf16x8 a[4], b[4];
#pragma unroll
      for (int mt = 0; mt < 4; mt++)
        a[mt] = *(const bf16x8*)&As[(wm * 64 + mt * 16 + l15) * G1_LDA + ks * 32 + quad * 8];
#pragma unroll
      for (int nt = 0; nt < 4; nt++)
        b[nt] = *(const bf16x8*)&Bs[(wn * 64 + nt * 16 + l15) * G1_LDA + ks * 32 + quad * 8];
#pragma unroll
      for (int mt = 0; mt < 4; mt++)
#pragma unroll
        for (int nt = 0; nt < 4; nt++)
          acc[mt][nt] = __builtin_amdgcn_mfma_f32_16x16x32_bf16(a[mt], b[nt], acc[mt][nt], 0, 0, 0);
    }
    __syncthreads();
  }

  // Epilogue: tanh, diag scale (lt only), bf16 store.
  float dscale[4];
#pragma unroll
  for (int nt = 0; nt < 4; nt++)
    dscale[nt] = is_lt ? diag[wn * 64 + nt * 16 + l15] : 1.0f;

#pragma unroll
  for (int mt = 0; mt < 4; mt++) {
#pragma unroll
    for (int r = 0; r < 4; r++) {
      int row = wm * 64 + mt * 16 + quad * 4 + r;
#pragma unroll
      for (int nt = 0; nt < 4; nt++) {
        int col = wn * 64 + nt * 16 + l15;
        float t = tanh_fast(acc[mt][nt][r]) * dscale[nt];
        O[(size_t)row * 256 + col] = f2bf(t);
      }
    }
  }
}

// ---------------------------------------------------------------------------
// Kernel 2: per-batch logits GEMM (lt_b @ rt_b^T, K=256) fused with exact
// softmax over the full R=512 row held in registers. Block = 64 L-rows x
// all 512 R-cols, 8 waves (one 64x64 region each), BK=32.
// ---------------------------------------------------------------------------
#define G2_LD 40

__global__ __launch_bounds__(512) void k_attn(
    const unsigned short* __restrict__ Lt, const unsigned short* __restrict__ Rt,
    float* __restrict__ Out) {
  __shared__ __align__(16) unsigned short Ls[64 * G2_LD];
  __shared__ __align__(16) unsigned short Rs[512 * G2_LD];
  __shared__ float red[8][64];
  __shared__ float rowv[64];

  int bx = blockIdx.x;              // 0..511
  int b  = bx >> 3;
  int l0 = (bx & 7) * 64;
  const unsigned short* Lb = Lt + ((size_t)b * 512 + l0) * 256;
  const unsigned short* Rb = Rt + (size_t)b * 512 * 256;
  float* Ob = Out + ((size_t)b * 512 + l0) * 512;

  int tid  = threadIdx.x;
  int lane = tid & 63;
  int wid  = tid >> 6;              // wave -> 64-col slice
  int l15  = lane & 15;
  int quad = lane >> 4;

  f32x4 zero = {0.0f, 0.0f, 0.0f, 0.0f};
  f32x4 acc[4][4];
#pragma unroll
  for (int i = 0; i < 4; i++)
#pragma unroll
    for (int j = 0; j < 4; j++) acc[i][j] = zero;

  for (int k0 = 0; k0 < 256; k0 += 32) {
    if (tid < 256) {                // Stage Lt: 64 x 32
      int r = tid >> 2, kc = tid & 3;
      *(uint4*)&Ls[r * G2_LD + kc * 8] = *(const uint4*)&Lb[r * 256 + k0 + kc * 8];
    }
#pragma unroll
    for (int i = 0; i < 4; i++) {   // Stage Rt: 512 x 32
      int seg = tid + i * 512;
      int r = seg >> 2, kc = seg & 3;
      *(uint4*)&Rs[r * G2_LD + kc * 8] = *(const uint4*)&Rb[r * 256 + k0 + kc * 8];
    }
    __syncthreads();

    bf16x8 a[4], bb[4];
#pragma unroll
    for (int mt = 0; mt < 4; mt++)
      a[mt] = *(const bf16x8*)&Ls[(mt * 16 + l15) * G2_LD + quad * 8];
#pragma unroll
    for (int nt = 0; nt < 4; nt++)
      bb[nt] = *(const bf16x8*)&Rs[(wid * 64 + nt * 16 + l15) * G2_LD + quad * 8];
#pragma unroll
    for (int mt = 0; mt < 4; mt++)
#pragma unroll
      for (int nt = 0; nt < 4; nt++)
        acc[mt][nt] = __builtin_amdgcn_mfma_f32_16x16x32_bf16(a[mt], bb[nt], acc[mt][nt], 0, 0, 0);
    __syncthreads();
  }

  // -------- softmax over the 512-wide row (split across 8 waves) --------
  // 1) row max: per-lane over nt, butterfly over the 16 lanes of the quad,
  //    then cross-wave via LDS.
#pragma unroll
  for (int mt = 0; mt < 4; mt++) {
#pragma unroll
    for (int r = 0; r < 4; r++) {
      float m = fmaxf(fmaxf(acc[mt][0][r], acc[mt][1][r]),
                      fmaxf(acc[mt][2][r], acc[mt][3][r]));
      m = fmaxf(m, __shfl_xor(m, 1));
      m = fmaxf(m, __shfl_xor(m, 2));
      m = fmaxf(m, __shfl_xor(m, 4));
      m = fmaxf(m, __shfl_xor(m, 8));
      if (l15 == 0) red[wid][mt * 16 + quad * 4 + r] = m;
    }
  }
  __syncthreads();
  if (tid < 64) {
    float m = red[0][tid];
#pragma unroll
    for (int w = 1; w < 8; w++) m = fmaxf(m, red[w][tid]);
    rowv[tid] = m;
  }
  __syncthreads();

  // 2) exp + row sum
#pragma unroll
  for (int mt = 0; mt < 4; mt++) {
#pragma unroll
    for (int r = 0; r < 4; r++) {
      float base = rowv[mt * 16 + quad * 4 + r];
      float s = 0.0f;
#pragma unroll
      for (int nt = 0; nt < 4; nt++) {
        float e = __expf(acc[mt][nt][r] - base);
        acc[mt][nt][r] = e;
        s += e;
      }
      s += __shfl_xor(s, 1);
      s += __shfl_xor(s, 2);
      s += __shfl_xor(s, 4);
      s += __shfl_xor(s, 8);
      if (l15 == 0) red[wid][mt * 16 + quad * 4 + r] = s;
    }
  }
  __syncthreads();
  if (tid < 64) {
    float s = red[0][tid];
#pragma unroll
    for (int w = 1; w < 8; w++) s += red[w][tid];
    rowv[tid] = 1.0f / s;
  }
  __syncthreads();

  // 3) scale + store fp32 output
#pragma unroll
  for (int mt = 0; mt < 4; mt++) {
#pragma unroll
    for (int r = 0; r < 4; r++) {
      int row = mt * 16 + quad * 4 + r;
      float inv = rowv[row];
#pragma unroll
      for (int nt = 0; nt < 4; nt++) {
        int col = wid * 64 + nt * 16 + l15;
        Ob[(size_t)row * 512 + col] = acc[mt][nt][r] * inv;
      }
    }
  }
}

// ---------------------------------------------------------------------------
extern "C" void kernel_launch(void* const* d_in, const int* in_sizes, int n_in,
                              void* d_out, int out_size, void* d_ws, size_t ws_size,
                              hipStream_t stream) {
  const float* lstm_lt = (const float*)d_in[0];   // (64,512,512)
  const float* lstm_rt = (const float*)d_in[1];   // (64,512,512)
  const float* W       = (const float*)d_in[2];   // (512,256)
  const float* diag    = (const float*)d_in[3];   // (256)
  float* out = (float*)d_out;                     // (64,512,512)

  // Workspace layout: Wt bf16 [256,512] | lt bf16 [32768,256] | rt bf16 [32768,256]
  unsigned short* Wt  = (unsigned short*)d_ws;
  unsigned short* Olt = (unsigned short*)((char*)d_ws + (size_t)256 * 512 * 2);
  unsigned short* Ort = Olt + (size_t)32768 * 256;

  k_wt<<<dim3(256), dim3(128), 0, stream>>>(W, Wt);
  k_proj<<<dim3(512), dim3(512), 0, stream>>>(lstm_lt, lstm_rt, Wt, diag, Olt, Ort);
  k_attn<<<dim3(512), dim3(512), 0, stream>>>(Olt, Ort, out);
}